// Round 6
// baseline (260.544 us; speedup 1.0000x reference)
//
#include <hip/hip_runtime.h>
#include <hip/hip_bf16.h>
#include <cstdint>
#include <cstddef>

// Problem constants (L=256, C=20, LC=5120, BATCH=1024)
#define LCN 5120
#define BN  1024
#define CN  20

typedef __attribute__((ext_vector_type(4))) float  floatx4;
typedef __attribute__((ext_vector_type(8))) short  shortx8;
typedef __attribute__((ext_vector_type(4))) unsigned short ushortx4;
typedef __attribute__((ext_vector_type(8))) unsigned short ushortx8;

static __device__ __forceinline__ unsigned short f2bf(float f) {
    __hip_bfloat16 h = __float2bfloat16(f);
    return *reinterpret_cast<unsigned short*>(&h);
}

static __device__ __forceinline__ void gload_lds16(const void* g, void* l) {
    __builtin_amdgcn_global_load_lds(
        (const __attribute__((address_space(1))) void*)g,
        (__attribute__((address_space(3))) void*)l,
        16, 0, 0);
}

// ---------------------------------------------------------------------------
// Pass 1: fused  out[b] = theta_0 + sum_i theta_lc[i]*x[b,i]  (fp32, exact)
//         and    Xb[b,i] = bf16(x[b,i])
// ---------------------------------------------------------------------------
__global__ __launch_bounds__(256) void k_init(const float* __restrict__ x,
                                              const float* __restrict__ th0,
                                              const float* __restrict__ thlc,
                                              float* __restrict__ out,
                                              unsigned short* __restrict__ Xb) {
    const int b = blockIdx.x;
    const int tid = threadIdx.x;
    const floatx4* xr = reinterpret_cast<const floatx4*>(x + (size_t)b * LCN);
    const floatx4* tr = reinterpret_cast<const floatx4*>(thlc);
    ushortx4* xw = reinterpret_cast<ushortx4*>(Xb + (size_t)b * LCN);
    float s = 0.0f;
    for (int k = tid; k < LCN / 4; k += 256) {
        const floatx4 a = xr[k], t2 = tr[k];
        s += a[0] * t2[0] + a[1] * t2[1] + a[2] * t2[2] + a[3] * t2[3];
        ushortx4 o;
#pragma unroll
        for (int e = 0; e < 4; ++e) o[e] = f2bf(a[e]);
        xw[k] = o;
    }
#pragma unroll
    for (int off = 32; off > 0; off >>= 1) s += __shfl_down(s, off, 64);
    __shared__ float ws4[4];
    if ((tid & 63) == 0) ws4[tid >> 6] = s;
    __syncthreads();
    if (tid == 0) out[b] = th0[0] + ws4[0] + ws4[1] + ws4[2] + ws4[3];
}

// ---------------------------------------------------------------------------
// Pass 2: FUSED masked-GEMM + dot-reduce. B-operand reads theta fp32 DIRECTLY
// (no pre-conversion pass): global fp32 -> VGPR (prefetched 2 iters ahead) ->
// mask+cvt bf16 -> ds_write_b128 into swizzled LDS. A staged via
// global_load_lds from Xb (ping-pong dbuf, one barrier/iter).
//   Z[b,a] = sum_k Xb[b,k] * bf16(theta[a,k] masked)
//   out[b] += sum_a Z[b,a] * x[b,a]
// Mask: theta row a contributes only k >= kmin(a) = 20*(a/20+1) (suffix).
// XCD-pinned decode + segment swizzle (conflicts=0) unchanged.
// ---------------------------------------------------------------------------
__global__ __launch_bounds__(256) void k_quad(
    const unsigned short* __restrict__ Xb,   // [1024][5120] bf16
    const float*          __restrict__ Th,   // [5120][5120] fp32 theta_lclc
    float*                __restrict__ out,  // [1024]
    const int tot)                           // total chunk count (220)
{
    const int bid  = blockIdx.x;
    const int xcd  = bid & 7;
    const int slot = bid >> 3;
    const int m    = slot & 7;
    const int g    = slot >> 3;
    int q = g * 8 + xcd;
    if (q >= tot) return;

    __shared__ unsigned short As[2][128 * 32];
    __shared__ unsigned short Bs[2][128 * 32];
    __shared__ float partial[128];

    const int tid  = threadIdx.x;
    const int lane = tid & 63;
    const int w    = tid >> 6;        // wave 0..3
    const int wm   = w & 1;
    const int wn   = w >> 1;
    const int lrow = lane & 15;
    const int kq   = lane >> 4;

    // map chunk ordinal q -> (n-tile, absolute chunk c)
    int n = 0, c = 0;
    for (int t = 0; t < 40; ++t) {
        const int c0t = (CN * ((128 * t) / CN + 1)) / 512;
        const int chn = 10 - c0t;
        if (q < chn) { n = t; c = c0t + q; break; }
        q -= chn;
    }
    const int b0 = m * 128;
    const int n0 = n * 128;
    const int k0 = c * 512;

    if (tid < 128) partial[tid] = 0.0f;

    floatx4 acc[4][4];
#pragma unroll
    for (int mt = 0; mt < 4; ++mt)
#pragma unroll
        for (int nt = 0; nt < 4; ++nt) acc[mt][nt] = (floatx4)0.0f;

    // per-thread staging constants. Thread handles 2 LDS slots s = t*256+tid;
    // slot s = (row, lseg) with row=s>>2, lseg=s&3; holds global 16B segment
    // gseg = (lseg - (row>>1)) & 3 of that row.
    int grow[2], goff[2], loffA[2], sbyte[2], kmin2[2];
#pragma unroll
    for (int t = 0; t < 2; ++t) {
        const int s    = t * 256 + tid;
        const int row  = s >> 2;
        const int gseg = ((s & 3) - (row >> 1)) & 3;
        grow[t]  = row;
        goff[t]  = gseg * 8;
        loffA[t] = (t * 256 + w * 64) * 16;   // wave-uniform byte offset
        sbyte[t] = s * 16;
        kmin2[t] = CN * ((n0 + row) / CN + 1);
    }
    // swizzled fragment offsets (ushort units): seg = (kq + (row>>1)) & 3
    int aoff[4], boff[4];
#pragma unroll
    for (int mt = 0; mt < 4; ++mt) {
        const int row = wm * 64 + mt * 16 + lrow;
        aoff[mt] = row * 32 + (((kq + (row >> 1)) & 3) << 3);
    }
#pragma unroll
    for (int nt = 0; nt < 4; ++nt) {
        const int row = wn * 64 + nt * 16 + lrow;
        boff[nt] = row * 32 + (((kq + (row >> 1)) & 3) << 3);
    }

    float br[2][8];      // B prefetch registers (fp32, one 32B strip per slot)

#define LOAD_B(KC)                                                             \
    {                                                                          \
        _Pragma("unroll")                                                      \
        for (int t = 0; t < 2; ++t) {                                          \
            const float* gp = Th + (size_t)(n0 + grow[t]) * LCN + (KC) + goff[t]; \
            const floatx4 v0 = *reinterpret_cast<const floatx4*>(gp);          \
            const floatx4 v1 = *reinterpret_cast<const floatx4*>(gp + 4);      \
            _Pragma("unroll")                                                  \
            for (int e = 0; e < 4; ++e) { br[t][e] = v0[e]; br[t][e + 4] = v1[e]; } \
        }                                                                      \
    }

#define CVT_WRITE_B(BUF, KC)                                                   \
    {                                                                          \
        _Pragma("unroll")                                                      \
        for (int t = 0; t < 2; ++t) {                                          \
            ushortx8 o;                                                        \
            _Pragma("unroll")                                                  \
            for (int e = 0; e < 8; ++e)                                        \
                o[e] = ((KC) + goff[t] + e >= kmin2[t]) ? f2bf(br[t][e])       \
                                                        : (unsigned short)0;  \
            *reinterpret_cast<ushortx8*>((char*)Bs[BUF] + sbyte[t]) = o;       \
        }                                                                      \
    }

    // prologue: stage chunk 0 (A via DMA, B via reg->cvt->LDS), prefetch B(1)
#pragma unroll
    for (int t = 0; t < 2; ++t)
        gload_lds16(Xb + (size_t)(b0 + grow[t]) * LCN + k0 + goff[t], (char*)As[0] + loffA[t]);
    LOAD_B(k0);
    CVT_WRITE_B(0, k0);
    LOAD_B(k0 + 32);

    for (int kk = 0; kk < 16; ++kk) {
        const int p = kk & 1;
        __syncthreads();   // drains A-DMA into As[p] + B ds_writes into Bs[p];
                           // fences last iter's reads of buf p^1
        if (kk < 15) {
            const int kcn = k0 + (kk + 1) * 32;
#pragma unroll
            for (int t = 0; t < 2; ++t)
                gload_lds16(Xb + (size_t)(b0 + grow[t]) * LCN + kcn + goff[t], (char*)As[p ^ 1] + loffA[t]);
            CVT_WRITE_B(p ^ 1, kcn);          // consumes br (B(kk+1))
            if (kk < 14) LOAD_B(k0 + (kk + 2) * 32);   // refill br (B(kk+2))
        }
        shortx8 af[4], bfr[4];
#pragma unroll
        for (int mt = 0; mt < 4; ++mt)
            af[mt] = *reinterpret_cast<const shortx8*>(As[p] + aoff[mt]);
#pragma unroll
        for (int nt = 0; nt < 4; ++nt)
            bfr[nt] = *reinterpret_cast<const shortx8*>(Bs[p] + boff[nt]);
#pragma unroll
        for (int mt = 0; mt < 4; ++mt)
#pragma unroll
            for (int nt = 0; nt < 4; ++nt)
                acc[mt][nt] = __builtin_amdgcn_mfma_f32_16x16x32_bf16(af[mt], bfr[nt], acc[mt][nt], 0, 0, 0);
    }

    // Epilogue: C/D layout col = lane&15 (a), row = quad*4 + reg (b)
#pragma unroll
    for (int mt = 0; mt < 4; ++mt) {
#pragma unroll
        for (int r = 0; r < 4; ++r) {
            const int b = b0 + wm * 64 + mt * 16 + kq * 4 + r;
            float s = 0.0f;
#pragma unroll
            for (int nt = 0; nt < 4; ++nt) {
                const int a = n0 + wn * 64 + nt * 16 + lrow;
                const __hip_bfloat16 hv = *reinterpret_cast<const __hip_bfloat16*>(&Xb[(size_t)b * LCN + a]);
                s += acc[mt][nt][r] * __bfloat162float(hv);
            }
            s += __shfl_xor(s, 1, 64);
            s += __shfl_xor(s, 2, 64);
            s += __shfl_xor(s, 4, 64);
            s += __shfl_xor(s, 8, 64);
            if (lrow == 0) atomicAdd(&partial[b - b0], s);
        }
    }
    __syncthreads();
    if (tid < 128) atomicAdd(&out[b0 + tid], partial[tid]);
#undef LOAD_B
#undef CVT_WRITE_B
}

// ---------------------------------------------------------------------------
extern "C" void kernel_launch(void* const* d_in, const int* in_sizes, int n_in,
                              void* d_out, int out_size, void* d_ws, size_t ws_size,
                              hipStream_t stream) {
    const float* x      = (const float*)d_in[0];
    const float* th0    = (const float*)d_in[1];
    const float* thlc   = (const float*)d_in[2];
    const float* thlclc = (const float*)d_in[3];
    float* out = (float*)d_out;

    // ws layout: Xb only (bf16 1024x5120 = 10.5 MB)
    unsigned short* Xb = (unsigned short*)d_ws;

    k_init<<<dim3(BN), 256, 0, stream>>>(x, th0, thlc, out, Xb);

    int tot = 0;
    for (int t = 0; t < 40; ++t) {
        const int c0t = (CN * ((128 * t) / CN + 1)) / 512;
        tot += 10 - c0t;
    }
    const int groups = (tot + 7) / 8;             // 28
    k_quad<<<dim3(groups * 64), 256, 0, stream>>>(Xb, thlclc, out, tot);
}